// Round 1
// baseline (7694.518 us; speedup 1.0000x reference)
//
#include <hip/hip_runtime.h>

#define N_USERS 100000
#define N_ITEMS 50000
#define N_TOT   150000
#define DIM     64
#define E_EDGES 3000000

__global__ void init_kernel(const float* __restrict__ user_emb,
                            const float* __restrict__ item_emb,
                            float* __restrict__ cur,
                            float* __restrict__ acc) {
    int i = blockIdx.x * blockDim.x + threadIdx.x;
    const int total = N_TOT * DIM;
    if (i < total) {
        float v = (i < N_USERS * DIM) ? user_emb[i] : item_emb[i - N_USERS * DIM];
        cur[i] = v;
        acc[i] = v;
    }
}

__global__ void zero_kernel(float* __restrict__ p, int n) {
    int i = blockIdx.x * blockDim.x + threadIdx.x;
    if (i < n) p[i] = 0.0f;
}

// 16 lanes per edge; each lane handles 4 consecutive features (float4 gather + 4 atomics)
__global__ void spmm_kernel(const int* __restrict__ rows,
                            const int* __restrict__ cols,
                            const float* __restrict__ vals,
                            const float* __restrict__ cur,
                            float* __restrict__ next) {
    int tid = blockIdx.x * blockDim.x + threadIdx.x;
    int e = tid >> 4;
    int q = (tid & 15) << 2;
    if (e < E_EDGES) {
        int r = rows[e];
        int c = cols[e];
        float v = vals[e];
        const float4 x = *reinterpret_cast<const float4*>(cur + (size_t)c * DIM + q);
        float* dst = next + (size_t)r * DIM + q;
        atomicAdd(dst + 0, v * x.x);
        atomicAdd(dst + 1, v * x.y);
        atomicAdd(dst + 2, v * x.z);
        atomicAdd(dst + 3, v * x.w);
    }
}

__global__ void accum_kernel(float* __restrict__ acc, const float* __restrict__ next, int n) {
    int i = blockIdx.x * blockDim.x + threadIdx.x;
    if (i < n) acc[i] += next[i];
}

__global__ void scale_kernel(float* __restrict__ acc, int n) {
    int i = blockIdx.x * blockDim.x + threadIdx.x;
    if (i < n) acc[i] *= 0.25f;
}

extern "C" void kernel_launch(void* const* d_in, const int* in_sizes, int n_in,
                              void* d_out, int out_size, void* d_ws, size_t ws_size,
                              hipStream_t stream) {
    const int*   rows     = (const int*)d_in[0];
    const int*   cols     = (const int*)d_in[1];
    const float* vals     = (const float*)d_in[2];
    const float* user_emb = (const float*)d_in[3];
    const float* item_emb = (const float*)d_in[4];
    float* out = (float*)d_out;

    float* cur = (float*)d_ws;
    float* nxt = cur + (size_t)N_TOT * DIM;

    const int total = N_TOT * DIM;
    const int tb = 256;
    dim3 blkTotal((total + tb - 1) / tb);

    init_kernel<<<blkTotal, tb, 0, stream>>>(user_emb, item_emb, cur, out);

    const long long spmm_threads = (long long)E_EDGES * 16;
    dim3 blkSpmm((unsigned)((spmm_threads + tb - 1) / tb));

    for (int layer = 0; layer < 3; ++layer) {
        zero_kernel<<<blkTotal, tb, 0, stream>>>(nxt, total);
        spmm_kernel<<<blkSpmm, tb, 0, stream>>>(rows, cols, vals, cur, nxt);
        accum_kernel<<<blkTotal, tb, 0, stream>>>(out, nxt, total);
        float* t = cur; cur = nxt; nxt = t;
    }
    scale_kernel<<<blkTotal, tb, 0, stream>>>(out, total);
}

// Round 2
// 874.277 us; speedup vs baseline: 8.8010x; 8.8010x over previous
//
#include <hip/hip_runtime.h>

#define N_USERS 100000
#define N_ITEMS 50000
#define N_TOT   150000
#define DIM     64
#define E_EDGES 3000000
#define NP1     (N_TOT + 1)
#define SCAN_B  256

// ---------------- common ----------------

__global__ void init_kernel(const float* __restrict__ user_emb,
                            const float* __restrict__ item_emb,
                            float* __restrict__ cur,
                            float* __restrict__ acc) {
    int i = blockIdx.x * blockDim.x + threadIdx.x;
    const int total = N_TOT * DIM;
    if (i < total) {
        float v = (i < N_USERS * DIM) ? user_emb[i] : item_emb[i - N_USERS * DIM];
        cur[i] = v;
        acc[i] = v;
    }
}

__global__ void zero_int_kernel(int* __restrict__ p, int n) {
    int i = blockIdx.x * blockDim.x + threadIdx.x;
    if (i < n) p[i] = 0;
}

// ---------------- CSR build ----------------

__global__ void hist_kernel(const int* __restrict__ rows, int* __restrict__ row_ptr) {
    int e = blockIdx.x * blockDim.x + threadIdx.x;
    if (e < E_EDGES) atomicAdd(&row_ptr[rows[e] + 1], 1);
}

// inclusive scan, per-block pass
__global__ void scan1_kernel(int* __restrict__ data, int n, int* __restrict__ bsums) {
    __shared__ int tmp[SCAN_B];
    int i = blockIdx.x * SCAN_B + threadIdx.x;
    int v = (i < n) ? data[i] : 0;
    tmp[threadIdx.x] = v;
    __syncthreads();
    for (int off = 1; off < SCAN_B; off <<= 1) {
        int t = (threadIdx.x >= off) ? tmp[threadIdx.x - off] : 0;
        __syncthreads();
        tmp[threadIdx.x] += t;
        __syncthreads();
    }
    if (i < n) data[i] = tmp[threadIdx.x];
    if (threadIdx.x == SCAN_B - 1) bsums[blockIdx.x] = tmp[SCAN_B - 1];
}

// single-block exclusive scan of block sums (in place)
__global__ void scan2_kernel(int* __restrict__ bsums, int nb) {
    __shared__ int tmp[SCAN_B];
    __shared__ int carry;
    if (threadIdx.x == 0) carry = 0;
    __syncthreads();
    for (int base = 0; base < nb; base += SCAN_B) {
        int i = base + threadIdx.x;
        int v = (i < nb) ? bsums[i] : 0;
        tmp[threadIdx.x] = v;
        __syncthreads();
        for (int off = 1; off < SCAN_B; off <<= 1) {
            int t = (threadIdx.x >= off) ? tmp[threadIdx.x - off] : 0;
            __syncthreads();
            tmp[threadIdx.x] += t;
            __syncthreads();
        }
        if (i < nb) bsums[i] = tmp[threadIdx.x] - v + carry;  // exclusive
        __syncthreads();
        if (threadIdx.x == SCAN_B - 1) carry += tmp[SCAN_B - 1];
        __syncthreads();
    }
}

__global__ void scan3_kernel(int* __restrict__ data, int n, const int* __restrict__ bsums) {
    int i = blockIdx.x * SCAN_B + threadIdx.x;
    if (i < n) data[i] += bsums[blockIdx.x];
}

__global__ void scatter_kernel(const int* __restrict__ rows, const int* __restrict__ cols,
                               const float* __restrict__ vals,
                               const int* __restrict__ row_ptr, int* __restrict__ fill,
                               int2* __restrict__ sedge) {
    int e = blockIdx.x * blockDim.x + threadIdx.x;
    if (e < E_EDGES) {
        int r = rows[e];
        int pos = row_ptr[r] + atomicAdd(&fill[r], 1);
        sedge[pos] = make_int2(cols[e], __float_as_int(vals[e]));
    }
}

// ---------------- CSR SpMM: one wave per row, lane = feature ----------------

__global__ void spmm_csr_kernel(const int* __restrict__ row_ptr,
                                const int2* __restrict__ sedge,
                                const float* __restrict__ cur,
                                float* __restrict__ nxt,
                                float* __restrict__ acc,
                                int last) {
    int wid = (blockIdx.x * blockDim.x + threadIdx.x) >> 6;
    int lane = threadIdx.x & 63;
    if (wid >= N_TOT) return;
    int beg = row_ptr[wid];
    int end = row_ptr[wid + 1];
    float s = 0.0f;
    int j = beg;
    for (; j + 1 < end; j += 2) {
        int2 e0 = sedge[j];
        int2 e1 = sedge[j + 1];
        s += __int_as_float(e0.y) * cur[(size_t)e0.x * DIM + lane];
        s += __int_as_float(e1.y) * cur[(size_t)e1.x * DIM + lane];
    }
    if (j < end) {
        int2 e0 = sedge[j];
        s += __int_as_float(e0.y) * cur[(size_t)e0.x * DIM + lane];
    }
    size_t o = (size_t)wid * DIM + lane;
    if (last) {
        acc[o] = (acc[o] + s) * 0.25f;
    } else {
        acc[o] += s;
        nxt[o] = s;
    }
}

// ---------------- fallback (round-0 atomic path) ----------------

__global__ void zero_f_kernel(float* __restrict__ p, int n) {
    int i = blockIdx.x * blockDim.x + threadIdx.x;
    if (i < n) p[i] = 0.0f;
}

__global__ void spmm_atomic_kernel(const int* __restrict__ rows, const int* __restrict__ cols,
                                   const float* __restrict__ vals,
                                   const float* __restrict__ cur, float* __restrict__ next) {
    int tid = blockIdx.x * blockDim.x + threadIdx.x;
    int e = tid >> 4;
    int q = (tid & 15) << 2;
    if (e < E_EDGES) {
        int r = rows[e];
        int c = cols[e];
        float v = vals[e];
        const float4 x = *reinterpret_cast<const float4*>(cur + (size_t)c * DIM + q);
        float* dst = next + (size_t)r * DIM + q;
        atomicAdd(dst + 0, v * x.x);
        atomicAdd(dst + 1, v * x.y);
        atomicAdd(dst + 2, v * x.z);
        atomicAdd(dst + 3, v * x.w);
    }
}

__global__ void accum_kernel(float* __restrict__ acc, const float* __restrict__ next, int n) {
    int i = blockIdx.x * blockDim.x + threadIdx.x;
    if (i < n) acc[i] += next[i];
}

__global__ void scale_kernel(float* __restrict__ acc, int n) {
    int i = blockIdx.x * blockDim.x + threadIdx.x;
    if (i < n) acc[i] *= 0.25f;
}

// ---------------- launch ----------------

extern "C" void kernel_launch(void* const* d_in, const int* in_sizes, int n_in,
                              void* d_out, int out_size, void* d_ws, size_t ws_size,
                              hipStream_t stream) {
    const int*   rows     = (const int*)d_in[0];
    const int*   cols     = (const int*)d_in[1];
    const float* vals     = (const float*)d_in[2];
    const float* user_emb = (const float*)d_in[3];
    const float* item_emb = (const float*)d_in[4];
    float* acc = (float*)d_out;

    const int total = N_TOT * DIM;
    const int tb = 256;
    dim3 blkTotal((total + tb - 1) / tb);
    dim3 blkE((E_EDGES + tb - 1) / tb);

    // workspace layout
    float* cur = (float*)d_ws;
    float* nxt = cur + (size_t)total;
    int2*  sedge   = (int2*)(nxt + (size_t)total);
    int*   row_ptr = (int*)(sedge + (size_t)E_EDGES);
    int*   fill    = row_ptr + NP1;
    int*   bsums   = fill + N_TOT;
    const int nb_scan = (NP1 + SCAN_B - 1) / SCAN_B;   // 587
    size_t need = (size_t)(bsums + nb_scan) - (size_t)d_ws;

    if (ws_size >= need) {
        // CSR path
        zero_int_kernel<<<(2 * N_TOT + 1 + tb - 1) / tb, tb, 0, stream>>>(row_ptr, 2 * N_TOT + 1);
        hist_kernel<<<blkE, tb, 0, stream>>>(rows, row_ptr);
        scan1_kernel<<<nb_scan, SCAN_B, 0, stream>>>(row_ptr, NP1, bsums);
        scan2_kernel<<<1, SCAN_B, 0, stream>>>(bsums, nb_scan);
        scan3_kernel<<<nb_scan, SCAN_B, 0, stream>>>(row_ptr, NP1, bsums);
        scatter_kernel<<<blkE, tb, 0, stream>>>(rows, cols, vals, row_ptr, fill, sedge);

        init_kernel<<<blkTotal, tb, 0, stream>>>(user_emb, item_emb, cur, acc);

        const int waves_per_block = tb / 64;
        dim3 blkRows((N_TOT + waves_per_block - 1) / waves_per_block);
        for (int layer = 0; layer < 3; ++layer) {
            int last = (layer == 2);
            spmm_csr_kernel<<<blkRows, tb, 0, stream>>>(row_ptr, sedge, cur, nxt, acc, last);
            float* t = cur; cur = nxt; nxt = t;
        }
    } else {
        // fallback: atomic scatter path
        init_kernel<<<blkTotal, tb, 0, stream>>>(user_emb, item_emb, cur, acc);
        const long long spmm_threads = (long long)E_EDGES * 16;
        dim3 blkSpmm((unsigned)((spmm_threads + tb - 1) / tb));
        for (int layer = 0; layer < 3; ++layer) {
            zero_f_kernel<<<blkTotal, tb, 0, stream>>>(nxt, total);
            spmm_atomic_kernel<<<blkSpmm, tb, 0, stream>>>(rows, cols, vals, cur, nxt);
            accum_kernel<<<blkTotal, tb, 0, stream>>>(acc, nxt, total);
            float* t = cur; cur = nxt; nxt = t;
        }
        scale_kernel<<<blkTotal, tb, 0, stream>>>(acc, total);
    }
}

// Round 3
// 652.539 us; speedup vs baseline: 11.7917x; 1.3398x over previous
//
#include <hip/hip_runtime.h>

#define N_USERS 100000
#define N_ITEMS 50000
#define N_TOT   150000
#define DIM     64
#define E_EDGES 3000000
#define NP1     (N_TOT + 1)
#define SCAN_B  256

// ---------------- common ----------------

__global__ void init_kernel(const float* __restrict__ user_emb,
                            const float* __restrict__ item_emb,
                            float* __restrict__ cur,
                            float* __restrict__ acc) {
    int i = blockIdx.x * blockDim.x + threadIdx.x;
    const int total = N_TOT * DIM;
    if (i < total) {
        float v = (i < N_USERS * DIM) ? user_emb[i] : item_emb[i - N_USERS * DIM];
        cur[i] = v;
        acc[i] = v;
    }
}

__global__ void zero_int_kernel(int* __restrict__ p, int n) {
    int i = blockIdx.x * blockDim.x + threadIdx.x;
    if (i < n) p[i] = 0;
}

// ---------------- CSR build ----------------

__global__ void hist_kernel(const int* __restrict__ rows, int* __restrict__ row_ptr) {
    int e = blockIdx.x * blockDim.x + threadIdx.x;
    if (e < E_EDGES) atomicAdd(&row_ptr[rows[e] + 1], 1);
}

// inclusive scan, per-block pass
__global__ void scan1_kernel(int* __restrict__ data, int n, int* __restrict__ bsums) {
    __shared__ int tmp[SCAN_B];
    int i = blockIdx.x * SCAN_B + threadIdx.x;
    int v = (i < n) ? data[i] : 0;
    tmp[threadIdx.x] = v;
    __syncthreads();
    for (int off = 1; off < SCAN_B; off <<= 1) {
        int t = (threadIdx.x >= off) ? tmp[threadIdx.x - off] : 0;
        __syncthreads();
        tmp[threadIdx.x] += t;
        __syncthreads();
    }
    if (i < n) data[i] = tmp[threadIdx.x];
    if (threadIdx.x == SCAN_B - 1) bsums[blockIdx.x] = tmp[SCAN_B - 1];
}

// single-block exclusive scan of block sums (in place)
__global__ void scan2_kernel(int* __restrict__ bsums, int nb) {
    __shared__ int tmp[SCAN_B];
    __shared__ int carry;
    if (threadIdx.x == 0) carry = 0;
    __syncthreads();
    for (int base = 0; base < nb; base += SCAN_B) {
        int i = base + threadIdx.x;
        int v = (i < nb) ? bsums[i] : 0;
        tmp[threadIdx.x] = v;
        __syncthreads();
        for (int off = 1; off < SCAN_B; off <<= 1) {
            int t = (threadIdx.x >= off) ? tmp[threadIdx.x - off] : 0;
            __syncthreads();
            tmp[threadIdx.x] += t;
            __syncthreads();
        }
        if (i < nb) bsums[i] = tmp[threadIdx.x] - v + carry;  // exclusive
        __syncthreads();
        if (threadIdx.x == SCAN_B - 1) carry += tmp[SCAN_B - 1];
        __syncthreads();
    }
}

__global__ void scan3_kernel(int* __restrict__ data, int n, const int* __restrict__ bsums) {
    int i = blockIdx.x * SCAN_B + threadIdx.x;
    if (i < n) data[i] += bsums[blockIdx.x];
}

__global__ void scatter_kernel(const int* __restrict__ rows, const int* __restrict__ cols,
                               const float* __restrict__ vals,
                               const int* __restrict__ row_ptr, int* __restrict__ fill,
                               int2* __restrict__ sedge) {
    int e = blockIdx.x * blockDim.x + threadIdx.x;
    if (e < E_EDGES) {
        int r = rows[e];
        int pos = row_ptr[r] + atomicAdd(&fill[r], 1);
        sedge[pos] = make_int2(cols[e], __float_as_int(vals[e]));
    }
}

// ---------------- CSR SpMM: one wave per row, lane = feature ----------------
// Edges pre-loaded lane-parallel (one coalesced vmem op), broadcast from
// registers via __shfl; gathers issued 8 at a time before a single wait.

#define GATHER8(K, GK)                                              \
    {                                                               \
        int jj = j0 + (K);                                          \
        int sl = (jj < cnt) ? jj : 0;                               \
        int col = __shfl(e.x, sl);                                  \
        float vv = __int_as_float(__shfl(e.y, sl));                 \
        if (jj >= cnt) vv = 0.0f;                                   \
        GK = vv * cur[(size_t)col * DIM + lane];                    \
    }

__global__ void spmm_csr_kernel(const int* __restrict__ row_ptr,
                                const int2* __restrict__ sedge,
                                const float* __restrict__ cur,
                                float* __restrict__ nxt,
                                float* __restrict__ acc,
                                int last) {
    int wid = (blockIdx.x * blockDim.x + threadIdx.x) >> 6;
    int lane = threadIdx.x & 63;
    if (wid >= N_TOT) return;
    int beg = row_ptr[wid];
    int end = row_ptr[wid + 1];
    float s = 0.0f;
    for (int base = beg; base < end; base += 64) {
        int cnt = min(64, end - base);
        int2 e = make_int2(0, 0);
        if (lane < cnt) e = sedge[base + lane];
        for (int j0 = 0; j0 < cnt; j0 += 8) {
            float g0, g1, g2, g3, g4, g5, g6, g7;
            GATHER8(0, g0); GATHER8(1, g1); GATHER8(2, g2); GATHER8(3, g3);
            GATHER8(4, g4); GATHER8(5, g5); GATHER8(6, g6); GATHER8(7, g7);
            s += ((g0 + g1) + (g2 + g3)) + ((g4 + g5) + (g6 + g7));
        }
    }
    size_t o = (size_t)wid * DIM + lane;
    if (last) {
        acc[o] = (acc[o] + s) * 0.25f;
    } else {
        acc[o] += s;
        nxt[o] = s;
    }
}

// ---------------- fallback (atomic path, used only if ws too small) ----------------

__global__ void zero_f_kernel(float* __restrict__ p, int n) {
    int i = blockIdx.x * blockDim.x + threadIdx.x;
    if (i < n) p[i] = 0.0f;
}

__global__ void spmm_atomic_kernel(const int* __restrict__ rows, const int* __restrict__ cols,
                                   const float* __restrict__ vals,
                                   const float* __restrict__ cur, float* __restrict__ next) {
    int tid = blockIdx.x * blockDim.x + threadIdx.x;
    int e = tid >> 4;
    int q = (tid & 15) << 2;
    if (e < E_EDGES) {
        int r = rows[e];
        int c = cols[e];
        float v = vals[e];
        const float4 x = *reinterpret_cast<const float4*>(cur + (size_t)c * DIM + q);
        float* dst = next + (size_t)r * DIM + q;
        atomicAdd(dst + 0, v * x.x);
        atomicAdd(dst + 1, v * x.y);
        atomicAdd(dst + 2, v * x.z);
        atomicAdd(dst + 3, v * x.w);
    }
}

__global__ void accum_kernel(float* __restrict__ acc, const float* __restrict__ next, int n) {
    int i = blockIdx.x * blockDim.x + threadIdx.x;
    if (i < n) acc[i] += next[i];
}

__global__ void scale_kernel(float* __restrict__ acc, int n) {
    int i = blockIdx.x * blockDim.x + threadIdx.x;
    if (i < n) acc[i] *= 0.25f;
}

// ---------------- launch ----------------

extern "C" void kernel_launch(void* const* d_in, const int* in_sizes, int n_in,
                              void* d_out, int out_size, void* d_ws, size_t ws_size,
                              hipStream_t stream) {
    const int*   rows     = (const int*)d_in[0];
    const int*   cols     = (const int*)d_in[1];
    const float* vals     = (const float*)d_in[2];
    const float* user_emb = (const float*)d_in[3];
    const float* item_emb = (const float*)d_in[4];
    float* acc = (float*)d_out;

    const int total = N_TOT * DIM;
    const int tb = 256;
    dim3 blkTotal((total + tb - 1) / tb);
    dim3 blkE((E_EDGES + tb - 1) / tb);

    // workspace layout
    float* cur = (float*)d_ws;
    float* nxt = cur + (size_t)total;
    int2*  sedge   = (int2*)(nxt + (size_t)total);
    int*   row_ptr = (int*)(sedge + (size_t)E_EDGES);
    int*   fill    = row_ptr + NP1;
    int*   bsums   = fill + N_TOT;
    const int nb_scan = (NP1 + SCAN_B - 1) / SCAN_B;   // 587
    size_t need = (size_t)(bsums + nb_scan) - (size_t)d_ws;

    if (ws_size >= need) {
        // CSR path
        zero_int_kernel<<<(2 * N_TOT + 1 + tb - 1) / tb, tb, 0, stream>>>(row_ptr, 2 * N_TOT + 1);
        hist_kernel<<<blkE, tb, 0, stream>>>(rows, row_ptr);
        scan1_kernel<<<nb_scan, SCAN_B, 0, stream>>>(row_ptr, NP1, bsums);
        scan2_kernel<<<1, SCAN_B, 0, stream>>>(bsums, nb_scan);
        scan3_kernel<<<nb_scan, SCAN_B, 0, stream>>>(row_ptr, NP1, bsums);
        scatter_kernel<<<blkE, tb, 0, stream>>>(rows, cols, vals, row_ptr, fill, sedge);

        init_kernel<<<blkTotal, tb, 0, stream>>>(user_emb, item_emb, cur, acc);

        const int waves_per_block = tb / 64;
        dim3 blkRows((N_TOT + waves_per_block - 1) / waves_per_block);
        for (int layer = 0; layer < 3; ++layer) {
            int last = (layer == 2);
            spmm_csr_kernel<<<blkRows, tb, 0, stream>>>(row_ptr, sedge, cur, nxt, acc, last);
            float* t = cur; cur = nxt; nxt = t;
        }
    } else {
        // fallback: atomic scatter path
        init_kernel<<<blkTotal, tb, 0, stream>>>(user_emb, item_emb, cur, acc);
        const long long spmm_threads = (long long)E_EDGES * 16;
        dim3 blkSpmm((unsigned)((spmm_threads + tb - 1) / tb));
        for (int layer = 0; layer < 3; ++layer) {
            zero_f_kernel<<<blkTotal, tb, 0, stream>>>(nxt, total);
            spmm_atomic_kernel<<<blkSpmm, tb, 0, stream>>>(rows, cols, vals, cur, nxt);
            accum_kernel<<<blkTotal, tb, 0, stream>>>(acc, nxt, total);
            float* t = cur; cur = nxt; nxt = t;
        }
        scale_kernel<<<blkTotal, tb, 0, stream>>>(acc, total);
    }
}

// Round 4
// 463.009 us; speedup vs baseline: 16.6185x; 1.4093x over previous
//
#include <hip/hip_runtime.h>

#define N_USERS 100000
#define N_ITEMS 50000
#define N_TOT   150000
#define DIM     64
#define E_EDGES 3000000
#define NP1     (N_TOT + 1)
#define NB1     586          // ceil(150000/256) coarse buckets (row >> 8)
#define EPB     4096         // edges per block in binning kernels

// ---------------- common ----------------

__global__ void init_kernel(const float* __restrict__ user_emb,
                            const float* __restrict__ item_emb,
                            float* __restrict__ cur,
                            float* __restrict__ acc) {
    int i = blockIdx.x * blockDim.x + threadIdx.x;
    const int total = N_TOT * DIM;
    if (i < total) {
        float v = (i < N_USERS * DIM) ? user_emb[i] : item_emb[i - N_USERS * DIM];
        cur[i] = v;
        acc[i] = v;
    }
}

__global__ void zero_int_kernel(int* __restrict__ p, int n) {
    int i = blockIdx.x * blockDim.x + threadIdx.x;
    if (i < n) p[i] = 0;
}

// ---------------- CSR build: two-level counting sort ----------------

// A1: coarse-bucket histogram (LDS-staged, one global atomic per bucket per block)
__global__ __launch_bounds__(256) void hist1_kernel(const int* __restrict__ rows,
                                                    int* __restrict__ hist1) {
    __shared__ int h[NB1];
    for (int b = threadIdx.x; b < NB1; b += 256) h[b] = 0;
    __syncthreads();
    int e0 = blockIdx.x * EPB;
    int cnt = min(EPB, E_EDGES - e0);
    for (int i = threadIdx.x; i < cnt; i += 256)
        atomicAdd(&h[rows[e0 + i] >> 8], 1);
    __syncthreads();
    for (int b = threadIdx.x; b < NB1; b += 256)
        if (h[b]) atomicAdd(&hist1[b], h[b]);
}

// A2: exclusive scan of 586 bucket counts -> bstart[0..586]
__global__ __launch_bounds__(256) void bscan_kernel(const int* __restrict__ hist1,
                                                    int* __restrict__ bstart) {
    __shared__ int psum[256];
    int t = threadIdx.x;
    int i0 = t * 3;
    int s0 = (i0     < NB1) ? hist1[i0]     : 0;
    int s1 = (i0 + 1 < NB1) ? hist1[i0 + 1] : 0;
    int s2 = (i0 + 2 < NB1) ? hist1[i0 + 2] : 0;
    int tsum = s0 + s1 + s2;
    psum[t] = tsum;
    __syncthreads();
    for (int off = 1; off < 256; off <<= 1) {
        int x = (t >= off) ? psum[t - off] : 0;
        __syncthreads();
        psum[t] += x;
        __syncthreads();
    }
    int excl = psum[t] - tsum;
    if (i0     < NB1) bstart[i0]     = excl;
    if (i0 + 1 < NB1) bstart[i0 + 1] = excl + s0;
    if (i0 + 2 < NB1) bstart[i0 + 2] = excl + s0 + s1;
    if (t == 255) bstart[NB1] = psum[255];
}

// A3: bin edges into coarse buckets. Edges staged in LDS ordered by bucket,
// then written out as coalesced runs of packed int2 {(row&255)<<24|col, val}.
__global__ __launch_bounds__(256) void bin_kernel(const int* __restrict__ rows,
                                                  const int* __restrict__ cols,
                                                  const float* __restrict__ vals,
                                                  const int* __restrict__ bstart,
                                                  int* __restrict__ fill1,
                                                  int2* __restrict__ tmp) {
    __shared__ int sw0[EPB];
    __shared__ int sw1[EPB];
    __shared__ unsigned short sbkt[EPB];
    __shared__ int hist[NB1];
    __shared__ int sstart[NB1];
    __shared__ int gbase[NB1];
    __shared__ int cursor[NB1];
    __shared__ int psum[256];

    int e0 = blockIdx.x * EPB;
    int cnt = min(EPB, E_EDGES - e0);

    for (int b = threadIdx.x; b < NB1; b += 256) hist[b] = 0;
    __syncthreads();

    int r[16], c[16]; float v[16];
#pragma unroll
    for (int k = 0; k < 16; ++k) {
        int i = threadIdx.x + k * 256;   // coalesced
        r[k] = -1;
        if (i < cnt) {
            int e = e0 + i;
            r[k] = rows[e];
            c[k] = cols[e];
            v[k] = vals[e];
            atomicAdd(&hist[r[k] >> 8], 1);
        }
    }
    __syncthreads();

    // block-wide exclusive scan over NB1 counters (3 per thread)
    int t = threadIdx.x;
    int i0 = t * 3;
    int s0 = (i0     < NB1) ? hist[i0]     : 0;
    int s1 = (i0 + 1 < NB1) ? hist[i0 + 1] : 0;
    int s2 = (i0 + 2 < NB1) ? hist[i0 + 2] : 0;
    int tsum = s0 + s1 + s2;
    psum[t] = tsum;
    __syncthreads();
    for (int off = 1; off < 256; off <<= 1) {
        int x = (t >= off) ? psum[t - off] : 0;
        __syncthreads();
        psum[t] += x;
        __syncthreads();
    }
    int excl = psum[t] - tsum;
    if (i0     < NB1) sstart[i0]     = excl;
    if (i0 + 1 < NB1) sstart[i0 + 1] = excl + s0;
    if (i0 + 2 < NB1) sstart[i0 + 2] = excl + s0 + s1;
    __syncthreads();

    // reserve global space per non-empty bucket; init local cursors
    for (int b = threadIdx.x; b < NB1; b += 256) {
        int h = hist[b];
        gbase[b] = (h > 0) ? (bstart[b] + atomicAdd(&fill1[b], h)) : 0;
        cursor[b] = sstart[b];
    }
    __syncthreads();

    // local scatter into LDS staging (ordered by bucket)
#pragma unroll
    for (int k = 0; k < 16; ++k) {
        if (r[k] >= 0) {
            int b = r[k] >> 8;
            int p = atomicAdd(&cursor[b], 1);
            sw0[p] = ((r[k] & 0xFF) << 24) | c[k];
            sw1[p] = __float_as_int(v[k]);
            sbkt[p] = (unsigned short)b;
        }
    }
    __syncthreads();

    // coalesced write-out: consecutive staged elems of a bucket -> consecutive global
    for (int i = threadIdx.x; i < cnt; i += 256) {
        int b = sbkt[i];
        int dest = gbase[b] + (i - sstart[b]);
        tmp[dest] = make_int2(sw0[i], sw1[i]);
    }
}

// B: per-bucket counting sort by row. Scatter stays inside the bucket's
// ~41 KB window (L2-resident -> full-line writebacks). Also emits row_ptr.
__global__ __launch_bounds__(256) void sort_kernel(const int2* __restrict__ tmp,
                                                   const int* __restrict__ bstart,
                                                   int* __restrict__ row_ptr,
                                                   int2* __restrict__ sedge) {
    int b = blockIdx.x;
    int beg = bstart[b], end = bstart[b + 1];
    __shared__ int hist[256];
    __shared__ int scn[256];
    __shared__ int cursor[256];
    int t = threadIdx.x;
    hist[t] = 0;
    __syncthreads();
    for (int i = beg + t; i < end; i += 256)
        atomicAdd(&hist[((unsigned)tmp[i].x) >> 24], 1);
    __syncthreads();
    int h = hist[t];
    scn[t] = h;
    __syncthreads();
    for (int off = 1; off < 256; off <<= 1) {
        int x = (t >= off) ? scn[t - off] : 0;
        __syncthreads();
        scn[t] += x;
        __syncthreads();
    }
    int excl = scn[t] - h;
    cursor[t] = excl;
    int row_id = b * 256 + t;
    if (row_id <= N_TOT) row_ptr[row_id] = beg + excl;
    __syncthreads();
    for (int i = beg + t; i < end; i += 256) {
        int2 rec = tmp[i];
        int lr = ((unsigned)rec.x) >> 24;
        int col = rec.x & 0xFFFFFF;
        int p = beg + atomicAdd(&cursor[lr], 1);
        sedge[p] = make_int2(col, rec.y);
    }
}

// ---------------- CSR SpMM: one wave per row, lane = feature ----------------

#define GATHER8(K, GK)                                              \
    {                                                               \
        int jj = j0 + (K);                                          \
        int sl = (jj < cnt) ? jj : 0;                               \
        int col = __shfl(e.x, sl);                                  \
        float vv = __int_as_float(__shfl(e.y, sl));                 \
        if (jj >= cnt) vv = 0.0f;                                   \
        GK = vv * cur[(size_t)col * DIM + lane];                    \
    }

__global__ void spmm_csr_kernel(const int* __restrict__ row_ptr,
                                const int2* __restrict__ sedge,
                                const float* __restrict__ cur,
                                float* __restrict__ nxt,
                                float* __restrict__ acc,
                                int last) {
    int wid = (blockIdx.x * blockDim.x + threadIdx.x) >> 6;
    int lane = threadIdx.x & 63;
    if (wid >= N_TOT) return;
    int beg = row_ptr[wid];
    int end = row_ptr[wid + 1];
    float s = 0.0f;
    for (int base = beg; base < end; base += 64) {
        int cnt = min(64, end - base);
        int2 e = make_int2(0, 0);
        if (lane < cnt) e = sedge[base + lane];
        for (int j0 = 0; j0 < cnt; j0 += 8) {
            float g0, g1, g2, g3, g4, g5, g6, g7;
            GATHER8(0, g0); GATHER8(1, g1); GATHER8(2, g2); GATHER8(3, g3);
            GATHER8(4, g4); GATHER8(5, g5); GATHER8(6, g6); GATHER8(7, g7);
            s += ((g0 + g1) + (g2 + g3)) + ((g4 + g5) + (g6 + g7));
        }
    }
    size_t o = (size_t)wid * DIM + lane;
    if (last) {
        acc[o] = (acc[o] + s) * 0.25f;
    } else {
        acc[o] += s;
        nxt[o] = s;
    }
}

// ---------------- fallback (atomic path, used only if ws too small) ----------------

__global__ void zero_f_kernel(float* __restrict__ p, int n) {
    int i = blockIdx.x * blockDim.x + threadIdx.x;
    if (i < n) p[i] = 0.0f;
}

__global__ void spmm_atomic_kernel(const int* __restrict__ rows, const int* __restrict__ cols,
                                   const float* __restrict__ vals,
                                   const float* __restrict__ cur, float* __restrict__ next) {
    int tid = blockIdx.x * blockDim.x + threadIdx.x;
    int e = tid >> 4;
    int q = (tid & 15) << 2;
    if (e < E_EDGES) {
        int r = rows[e];
        int c = cols[e];
        float v = vals[e];
        const float4 x = *reinterpret_cast<const float4*>(cur + (size_t)c * DIM + q);
        float* dst = next + (size_t)r * DIM + q;
        atomicAdd(dst + 0, v * x.x);
        atomicAdd(dst + 1, v * x.y);
        atomicAdd(dst + 2, v * x.z);
        atomicAdd(dst + 3, v * x.w);
    }
}

__global__ void accum_kernel(float* __restrict__ acc, const float* __restrict__ next, int n) {
    int i = blockIdx.x * blockDim.x + threadIdx.x;
    if (i < n) acc[i] += next[i];
}

__global__ void scale_kernel(float* __restrict__ acc, int n) {
    int i = blockIdx.x * blockDim.x + threadIdx.x;
    if (i < n) acc[i] *= 0.25f;
}

// ---------------- launch ----------------

extern "C" void kernel_launch(void* const* d_in, const int* in_sizes, int n_in,
                              void* d_out, int out_size, void* d_ws, size_t ws_size,
                              hipStream_t stream) {
    const int*   rows     = (const int*)d_in[0];
    const int*   cols     = (const int*)d_in[1];
    const float* vals     = (const float*)d_in[2];
    const float* user_emb = (const float*)d_in[3];
    const float* item_emb = (const float*)d_in[4];
    float* acc = (float*)d_out;

    const int total = N_TOT * DIM;
    const int tb = 256;
    dim3 blkTotal((total + tb - 1) / tb);

    // workspace layout (tmp overlaid on nxt: tmp dead before spmm writes nxt)
    float* cur = (float*)d_ws;
    float* nxt = cur + (size_t)total;
    int2*  tmp = (int2*)nxt;                        // 24 MB <= 38.4 MB
    int2*  sedge   = (int2*)(nxt + (size_t)total);
    int*   row_ptr = (int*)(sedge + (size_t)E_EDGES);
    int*   hist1   = row_ptr + NP1;
    int*   fill1   = hist1 + NB1;
    int*   bstart  = fill1 + NB1;                   // NB1+1 ints
    size_t need = (size_t)((char*)(bstart + NB1 + 1) - (char*)d_ws);

    const int grid_bin = (E_EDGES + EPB - 1) / EPB;  // 733

    if (ws_size >= need) {
        zero_int_kernel<<<(2 * NB1 + tb - 1) / tb, tb, 0, stream>>>(hist1, 2 * NB1);
        hist1_kernel<<<grid_bin, tb, 0, stream>>>(rows, hist1);
        bscan_kernel<<<1, tb, 0, stream>>>(hist1, bstart);
        bin_kernel<<<grid_bin, tb, 0, stream>>>(rows, cols, vals, bstart, fill1, tmp);
        sort_kernel<<<NB1, tb, 0, stream>>>(tmp, bstart, row_ptr, sedge);

        init_kernel<<<blkTotal, tb, 0, stream>>>(user_emb, item_emb, cur, acc);

        const int waves_per_block = tb / 64;
        dim3 blkRows((N_TOT + waves_per_block - 1) / waves_per_block);
        for (int layer = 0; layer < 3; ++layer) {
            int last = (layer == 2);
            spmm_csr_kernel<<<blkRows, tb, 0, stream>>>(row_ptr, sedge, cur, nxt, acc, last);
            float* t = cur; cur = nxt; nxt = t;
        }
    } else {
        // fallback: atomic scatter path
        init_kernel<<<blkTotal, tb, 0, stream>>>(user_emb, item_emb, cur, acc);
        const long long spmm_threads = (long long)E_EDGES * 16;
        dim3 blkSpmm((unsigned)((spmm_threads + tb - 1) / tb));
        for (int layer = 0; layer < 3; ++layer) {
            zero_f_kernel<<<blkTotal, tb, 0, stream>>>(nxt, total);
            spmm_atomic_kernel<<<blkSpmm, tb, 0, stream>>>(rows, cols, vals, cur, nxt);
            accum_kernel<<<blkTotal, tb, 0, stream>>>(acc, nxt, total);
            float* t = cur; cur = nxt; nxt = t;
        }
        scale_kernel<<<blkTotal, tb, 0, stream>>>(acc, total);
    }
}

// Round 5
// 362.082 us; speedup vs baseline: 21.2507x; 1.2787x over previous
//
#include <hip/hip_runtime.h>
#include <hip/hip_fp16.h>

#define N_USERS 100000
#define N_ITEMS 50000
#define N_TOT   150000
#define DIM     64
#define E_EDGES 3000000
#define NP1     (N_TOT + 1)
#define NB1     586          // ceil(150000/256) coarse buckets (row >> 8)
#define EPB     4096         // edges per block in binning kernels

// ---------------- common ----------------

// after CSR build: acc (fp32, d_out) and cur (fp16 propagation buffer)
__global__ void init_kernel(const float* __restrict__ user_emb,
                            const float* __restrict__ item_emb,
                            __half* __restrict__ cur,
                            float* __restrict__ acc) {
    int i = blockIdx.x * blockDim.x + threadIdx.x;
    const int total4 = N_TOT * DIM / 4;
    if (i < total4) {
        int base = i * 4;
        float4 v = (base < N_USERS * DIM)
                     ? reinterpret_cast<const float4*>(user_emb)[i]
                     : reinterpret_cast<const float4*>(item_emb)[(base - N_USERS * DIM) >> 2];
        reinterpret_cast<float4*>(acc)[i] = v;
        __half2 h0 = __floats2half2_rn(v.x, v.y);
        __half2 h1 = __floats2half2_rn(v.z, v.w);
        reinterpret_cast<__half2*>(cur)[i * 2]     = h0;
        reinterpret_cast<__half2*>(cur)[i * 2 + 1] = h1;
    }
}

__global__ void zero_int_kernel(int* __restrict__ p, int n) {
    int i = blockIdx.x * blockDim.x + threadIdx.x;
    if (i < n) p[i] = 0;
}

// ---------------- CSR build: two-level counting sort ----------------

__global__ __launch_bounds__(256) void hist1_kernel(const int* __restrict__ rows,
                                                    int* __restrict__ hist1) {
    __shared__ int h[NB1];
    for (int b = threadIdx.x; b < NB1; b += 256) h[b] = 0;
    __syncthreads();
    int e0 = blockIdx.x * EPB;
    int cnt = min(EPB, E_EDGES - e0);
    for (int i = threadIdx.x; i < cnt; i += 256)
        atomicAdd(&h[rows[e0 + i] >> 8], 1);
    __syncthreads();
    for (int b = threadIdx.x; b < NB1; b += 256)
        if (h[b]) atomicAdd(&hist1[b], h[b]);
}

__global__ __launch_bounds__(256) void bscan_kernel(const int* __restrict__ hist1,
                                                    int* __restrict__ bstart) {
    __shared__ int psum[256];
    int t = threadIdx.x;
    int i0 = t * 3;
    int s0 = (i0     < NB1) ? hist1[i0]     : 0;
    int s1 = (i0 + 1 < NB1) ? hist1[i0 + 1] : 0;
    int s2 = (i0 + 2 < NB1) ? hist1[i0 + 2] : 0;
    int tsum = s0 + s1 + s2;
    psum[t] = tsum;
    __syncthreads();
    for (int off = 1; off < 256; off <<= 1) {
        int x = (t >= off) ? psum[t - off] : 0;
        __syncthreads();
        psum[t] += x;
        __syncthreads();
    }
    int excl = psum[t] - tsum;
    if (i0     < NB1) bstart[i0]     = excl;
    if (i0 + 1 < NB1) bstart[i0 + 1] = excl + s0;
    if (i0 + 2 < NB1) bstart[i0 + 2] = excl + s0 + s1;
    if (t == 255) bstart[NB1] = psum[255];
}

__global__ __launch_bounds__(256) void bin_kernel(const int* __restrict__ rows,
                                                  const int* __restrict__ cols,
                                                  const float* __restrict__ vals,
                                                  const int* __restrict__ bstart,
                                                  int* __restrict__ fill1,
                                                  int2* __restrict__ tmp) {
    __shared__ int sw0[EPB];
    __shared__ int sw1[EPB];
    __shared__ unsigned short sbkt[EPB];
    __shared__ int hist[NB1];
    __shared__ int sstart[NB1];
    __shared__ int gbase[NB1];
    __shared__ int cursor[NB1];
    __shared__ int psum[256];

    int e0 = blockIdx.x * EPB;
    int cnt = min(EPB, E_EDGES - e0);

    for (int b = threadIdx.x; b < NB1; b += 256) hist[b] = 0;
    __syncthreads();

    int r[16], c[16]; float v[16];
#pragma unroll
    for (int k = 0; k < 16; ++k) {
        int i = threadIdx.x + k * 256;   // coalesced
        r[k] = -1;
        if (i < cnt) {
            int e = e0 + i;
            r[k] = rows[e];
            c[k] = cols[e];
            v[k] = vals[e];
            atomicAdd(&hist[r[k] >> 8], 1);
        }
    }
    __syncthreads();

    int t = threadIdx.x;
    int i0 = t * 3;
    int s0 = (i0     < NB1) ? hist[i0]     : 0;
    int s1 = (i0 + 1 < NB1) ? hist[i0 + 1] : 0;
    int s2 = (i0 + 2 < NB1) ? hist[i0 + 2] : 0;
    int tsum = s0 + s1 + s2;
    psum[t] = tsum;
    __syncthreads();
    for (int off = 1; off < 256; off <<= 1) {
        int x = (t >= off) ? psum[t - off] : 0;
        __syncthreads();
        psum[t] += x;
        __syncthreads();
    }
    int excl = psum[t] - tsum;
    if (i0     < NB1) sstart[i0]     = excl;
    if (i0 + 1 < NB1) sstart[i0 + 1] = excl + s0;
    if (i0 + 2 < NB1) sstart[i0 + 2] = excl + s0 + s1;
    __syncthreads();

    for (int b = threadIdx.x; b < NB1; b += 256) {
        int h = hist[b];
        gbase[b] = (h > 0) ? (bstart[b] + atomicAdd(&fill1[b], h)) : 0;
        cursor[b] = sstart[b];
    }
    __syncthreads();

#pragma unroll
    for (int k = 0; k < 16; ++k) {
        if (r[k] >= 0) {
            int b = r[k] >> 8;
            int p = atomicAdd(&cursor[b], 1);
            sw0[p] = ((r[k] & 0xFF) << 24) | c[k];
            sw1[p] = __float_as_int(v[k]);
            sbkt[p] = (unsigned short)b;
        }
    }
    __syncthreads();

    for (int i = threadIdx.x; i < cnt; i += 256) {
        int b = sbkt[i];
        int dest = gbase[b] + (i - sstart[b]);
        tmp[dest] = make_int2(sw0[i], sw1[i]);
    }
}

__global__ __launch_bounds__(256) void sort_kernel(const int2* __restrict__ tmp,
                                                   const int* __restrict__ bstart,
                                                   int* __restrict__ row_ptr,
                                                   int2* __restrict__ sedge) {
    int b = blockIdx.x;
    int beg = bstart[b], end = bstart[b + 1];
    __shared__ int hist[256];
    __shared__ int scn[256];
    __shared__ int cursor[256];
    int t = threadIdx.x;
    hist[t] = 0;
    __syncthreads();
    for (int i = beg + t; i < end; i += 256)
        atomicAdd(&hist[((unsigned)tmp[i].x) >> 24], 1);
    __syncthreads();
    int h = hist[t];
    scn[t] = h;
    __syncthreads();
    for (int off = 1; off < 256; off <<= 1) {
        int x = (t >= off) ? scn[t - off] : 0;
        __syncthreads();
        scn[t] += x;
        __syncthreads();
    }
    int excl = scn[t] - h;
    cursor[t] = excl;
    int row_id = b * 256 + t;
    if (row_id <= N_TOT) row_ptr[row_id] = beg + excl;
    __syncthreads();
    for (int i = beg + t; i < end; i += 256) {
        int2 rec = tmp[i];
        int lr = ((unsigned)rec.x) >> 24;
        int col = rec.x & 0xFFFFFF;
        int p = beg + atomicAdd(&cursor[lr], 1);
        sedge[p] = make_int2(col, rec.y);
    }
}

// ---------------- CSR SpMM: one wave per row, lane = feature, fp16 gather ----------------

#define GATHER8(K, GK)                                                  \
    {                                                                   \
        int jj = j0 + (K);                                              \
        int sl = (jj < cnt) ? jj : 0;                                   \
        int col = __shfl(e.x, sl);                                      \
        float vv = __int_as_float(__shfl(e.y, sl));                     \
        if (jj >= cnt) vv = 0.0f;                                       \
        GK = vv * __half2float(cur[(size_t)col * DIM + lane]);          \
    }

__global__ void spmm_csr_kernel(const int* __restrict__ row_ptr,
                                const int2* __restrict__ sedge,
                                const __half* __restrict__ cur,
                                __half* __restrict__ nxt,
                                float* __restrict__ acc,
                                int last) {
    int wid = (blockIdx.x * blockDim.x + threadIdx.x) >> 6;
    int lane = threadIdx.x & 63;
    if (wid >= N_TOT) return;
    int beg = row_ptr[wid];
    int end = row_ptr[wid + 1];
    float s = 0.0f;
    for (int base = beg; base < end; base += 64) {
        int cnt = min(64, end - base);
        int2 e = make_int2(0, 0);
        if (lane < cnt) e = sedge[base + lane];
        for (int j0 = 0; j0 < cnt; j0 += 8) {
            float g0, g1, g2, g3, g4, g5, g6, g7;
            GATHER8(0, g0); GATHER8(1, g1); GATHER8(2, g2); GATHER8(3, g3);
            GATHER8(4, g4); GATHER8(5, g5); GATHER8(6, g6); GATHER8(7, g7);
            s += ((g0 + g1) + (g2 + g3)) + ((g4 + g5) + (g6 + g7));
        }
    }
    size_t o = (size_t)wid * DIM + lane;
    if (last) {
        acc[o] = (acc[o] + s) * 0.25f;
    } else {
        acc[o] += s;
        nxt[o] = __float2half_rn(s);
    }
}

// ---------------- fallback (fp32 atomic path, used only if ws too small) ----------------

__global__ void initf_kernel(const float* __restrict__ user_emb,
                             const float* __restrict__ item_emb,
                             float* __restrict__ cur,
                             float* __restrict__ acc) {
    int i = blockIdx.x * blockDim.x + threadIdx.x;
    const int total = N_TOT * DIM;
    if (i < total) {
        float v = (i < N_USERS * DIM) ? user_emb[i] : item_emb[i - N_USERS * DIM];
        cur[i] = v;
        acc[i] = v;
    }
}

__global__ void zero_f_kernel(float* __restrict__ p, int n) {
    int i = blockIdx.x * blockDim.x + threadIdx.x;
    if (i < n) p[i] = 0.0f;
}

__global__ void spmm_atomic_kernel(const int* __restrict__ rows, const int* __restrict__ cols,
                                   const float* __restrict__ vals,
                                   const float* __restrict__ cur, float* __restrict__ next) {
    int tid = blockIdx.x * blockDim.x + threadIdx.x;
    int e = tid >> 4;
    int q = (tid & 15) << 2;
    if (e < E_EDGES) {
        int r = rows[e];
        int c = cols[e];
        float v = vals[e];
        const float4 x = *reinterpret_cast<const float4*>(cur + (size_t)c * DIM + q);
        float* dst = next + (size_t)r * DIM + q;
        atomicAdd(dst + 0, v * x.x);
        atomicAdd(dst + 1, v * x.y);
        atomicAdd(dst + 2, v * x.z);
        atomicAdd(dst + 3, v * x.w);
    }
}

__global__ void accum_kernel(float* __restrict__ acc, const float* __restrict__ next, int n) {
    int i = blockIdx.x * blockDim.x + threadIdx.x;
    if (i < n) acc[i] += next[i];
}

__global__ void scale_kernel(float* __restrict__ acc, int n) {
    int i = blockIdx.x * blockDim.x + threadIdx.x;
    if (i < n) acc[i] *= 0.25f;
}

// ---------------- launch ----------------

extern "C" void kernel_launch(void* const* d_in, const int* in_sizes, int n_in,
                              void* d_out, int out_size, void* d_ws, size_t ws_size,
                              hipStream_t stream) {
    const int*   rows     = (const int*)d_in[0];
    const int*   cols     = (const int*)d_in[1];
    const float* vals     = (const float*)d_in[2];
    const float* user_emb = (const float*)d_in[3];
    const float* item_emb = (const float*)d_in[4];
    float* acc = (float*)d_out;

    const int total = N_TOT * DIM;
    const int tb = 256;

    // workspace layout; tmp (24 MB) overlays cur_h+nxt_h (38.4 MB) — tmp is
    // dead before init_kernel writes cur_h (init runs after sort_kernel).
    __half* cur = (__half*)d_ws;
    __half* nxt = cur + (size_t)total;
    int2*  tmp = (int2*)d_ws;
    int2*  sedge   = (int2*)(nxt + (size_t)total);
    int*   row_ptr = (int*)(sedge + (size_t)E_EDGES);
    int*   hist1   = row_ptr + NP1;
    int*   fill1   = hist1 + NB1;
    int*   bstart  = fill1 + NB1;                   // NB1+1 ints
    size_t need = (size_t)((char*)(bstart + NB1 + 1) - (char*)d_ws);

    const int grid_bin = (E_EDGES + EPB - 1) / EPB;  // 733

    if (ws_size >= need) {
        zero_int_kernel<<<(2 * NB1 + tb - 1) / tb, tb, 0, stream>>>(hist1, 2 * NB1);
        hist1_kernel<<<grid_bin, tb, 0, stream>>>(rows, hist1);
        bscan_kernel<<<1, tb, 0, stream>>>(hist1, bstart);
        bin_kernel<<<grid_bin, tb, 0, stream>>>(rows, cols, vals, bstart, fill1, tmp);
        sort_kernel<<<NB1, tb, 0, stream>>>(tmp, bstart, row_ptr, sedge);

        dim3 blkInit((total / 4 + tb - 1) / tb);
        init_kernel<<<blkInit, tb, 0, stream>>>(user_emb, item_emb, cur, acc);

        const int waves_per_block = tb / 64;
        dim3 blkRows((N_TOT + waves_per_block - 1) / waves_per_block);
        for (int layer = 0; layer < 3; ++layer) {
            int last = (layer == 2);
            spmm_csr_kernel<<<blkRows, tb, 0, stream>>>(row_ptr, sedge, cur, nxt, acc, last);
            __half* t = cur; cur = nxt; nxt = t;
        }
    } else {
        // fallback: fp32 atomic scatter path
        float* fcur = (float*)d_ws;
        float* fnxt = fcur + (size_t)total;
        dim3 blkTotal((total + tb - 1) / tb);
        initf_kernel<<<blkTotal, tb, 0, stream>>>(user_emb, item_emb, fcur, acc);
        const long long spmm_threads = (long long)E_EDGES * 16;
        dim3 blkSpmm((unsigned)((spmm_threads + tb - 1) / tb));
        for (int layer = 0; layer < 3; ++layer) {
            zero_f_kernel<<<blkTotal, tb, 0, stream>>>(fnxt, total);
            spmm_atomic_kernel<<<blkSpmm, tb, 0, stream>>>(rows, cols, vals, fcur, fnxt);
            accum_kernel<<<blkTotal, tb, 0, stream>>>(acc, fnxt, total);
            float* t = fcur; fcur = fnxt; fnxt = t;
        }
        scale_kernel<<<blkTotal, tb, 0, stream>>>(acc, total);
    }
}

// Round 6
// 286.094 us; speedup vs baseline: 26.8951x; 1.2656x over previous
//
#include <hip/hip_runtime.h>
#include <hip/hip_fp16.h>

#define N_USERS 100000
#define N_ITEMS 50000
#define N_TOT   150000
#define DIM     64
#define E_EDGES 3000000
#define NP1     (N_TOT + 1)
#define NB1     586          // ceil(150000/256) coarse buckets (row >> 8)
#define EPB     4096         // edges per block in binning kernels

// ---------------- init: b0 = fp16(emb) ----------------

__global__ void init_kernel(const float* __restrict__ user_emb,
                            const float* __restrict__ item_emb,
                            __half2* __restrict__ b0) {
    int i = blockIdx.x * blockDim.x + threadIdx.x;
    const int total4 = N_TOT * DIM / 4;
    if (i < total4) {
        int base = i * 4;
        float4 v = (base < N_USERS * DIM)
                     ? reinterpret_cast<const float4*>(user_emb)[i]
                     : reinterpret_cast<const float4*>(item_emb)[(base - N_USERS * DIM) >> 2];
        b0[i * 2]     = __floats2half2_rn(v.x, v.y);
        b0[i * 2 + 1] = __floats2half2_rn(v.z, v.w);
    }
}

__global__ void zero_int_kernel(int* __restrict__ p, int n) {
    int i = blockIdx.x * blockDim.x + threadIdx.x;
    if (i < n) p[i] = 0;
}

// ---------------- CSR build: two-level counting sort ----------------

__global__ __launch_bounds__(256) void hist1_kernel(const int* __restrict__ rows,
                                                    int* __restrict__ hist1) {
    __shared__ int h[NB1];
    for (int b = threadIdx.x; b < NB1; b += 256) h[b] = 0;
    __syncthreads();
    int e0 = blockIdx.x * EPB;
    int cnt = min(EPB, E_EDGES - e0);
    for (int i = threadIdx.x; i < cnt; i += 256)
        atomicAdd(&h[rows[e0 + i] >> 8], 1);
    __syncthreads();
    for (int b = threadIdx.x; b < NB1; b += 256)
        if (h[b]) atomicAdd(&hist1[b], h[b]);
}

__global__ __launch_bounds__(256) void bscan_kernel(const int* __restrict__ hist1,
                                                    int* __restrict__ bstart) {
    __shared__ int psum[256];
    int t = threadIdx.x;
    int i0 = t * 3;
    int s0 = (i0     < NB1) ? hist1[i0]     : 0;
    int s1 = (i0 + 1 < NB1) ? hist1[i0 + 1] : 0;
    int s2 = (i0 + 2 < NB1) ? hist1[i0 + 2] : 0;
    int tsum = s0 + s1 + s2;
    psum[t] = tsum;
    __syncthreads();
    for (int off = 1; off < 256; off <<= 1) {
        int x = (t >= off) ? psum[t - off] : 0;
        __syncthreads();
        psum[t] += x;
        __syncthreads();
    }
    int excl = psum[t] - tsum;
    if (i0     < NB1) bstart[i0]     = excl;
    if (i0 + 1 < NB1) bstart[i0 + 1] = excl + s0;
    if (i0 + 2 < NB1) bstart[i0 + 2] = excl + s0 + s1;
    if (t == 255) bstart[NB1] = psum[255];
}

__global__ __launch_bounds__(256) void bin_kernel(const int* __restrict__ rows,
                                                  const int* __restrict__ cols,
                                                  const float* __restrict__ vals,
                                                  const int* __restrict__ bstart,
                                                  int* __restrict__ fill1,
                                                  int2* __restrict__ tmp) {
    __shared__ int sw0[EPB];
    __shared__ int sw1[EPB];
    __shared__ unsigned short sbkt[EPB];
    __shared__ int hist[NB1];
    __shared__ int sstart[NB1];
    __shared__ int gbase[NB1];
    __shared__ int cursor[NB1];
    __shared__ int psum[256];

    int e0 = blockIdx.x * EPB;
    int cnt = min(EPB, E_EDGES - e0);

    for (int b = threadIdx.x; b < NB1; b += 256) hist[b] = 0;
    __syncthreads();

    int r[16], c[16]; float v[16];
#pragma unroll
    for (int k = 0; k < 16; ++k) {
        int i = threadIdx.x + k * 256;   // coalesced
        r[k] = -1;
        if (i < cnt) {
            int e = e0 + i;
            r[k] = rows[e];
            c[k] = cols[e];
            v[k] = vals[e];
            atomicAdd(&hist[r[k] >> 8], 1);
        }
    }
    __syncthreads();

    int t = threadIdx.x;
    int i0 = t * 3;
    int s0 = (i0     < NB1) ? hist[i0]     : 0;
    int s1 = (i0 + 1 < NB1) ? hist[i0 + 1] : 0;
    int s2 = (i0 + 2 < NB1) ? hist[i0 + 2] : 0;
    int tsum = s0 + s1 + s2;
    psum[t] = tsum;
    __syncthreads();
    for (int off = 1; off < 256; off <<= 1) {
        int x = (t >= off) ? psum[t - off] : 0;
        __syncthreads();
        psum[t] += x;
        __syncthreads();
    }
    int excl = psum[t] - tsum;
    if (i0     < NB1) sstart[i0]     = excl;
    if (i0 + 1 < NB1) sstart[i0 + 1] = excl + s0;
    if (i0 + 2 < NB1) sstart[i0 + 2] = excl + s0 + s1;
    __syncthreads();

    for (int b = threadIdx.x; b < NB1; b += 256) {
        int h = hist[b];
        gbase[b] = (h > 0) ? (bstart[b] + atomicAdd(&fill1[b], h)) : 0;
        cursor[b] = sstart[b];
    }
    __syncthreads();

#pragma unroll
    for (int k = 0; k < 16; ++k) {
        if (r[k] >= 0) {
            int b = r[k] >> 8;
            int p = atomicAdd(&cursor[b], 1);
            sw0[p] = ((r[k] & 0xFF) << 24) | c[k];
            sw1[p] = __float_as_int(v[k]);
            sbkt[p] = (unsigned short)b;
        }
    }
    __syncthreads();

    for (int i = threadIdx.x; i < cnt; i += 256) {
        int b = sbkt[i];
        int dest = gbase[b] + (i - sstart[b]);
        tmp[dest] = make_int2(sw0[i], sw1[i]);
    }
}

__global__ __launch_bounds__(256) void sort_kernel(const int2* __restrict__ tmp,
                                                   const int* __restrict__ bstart,
                                                   int* __restrict__ row_ptr,
                                                   int2* __restrict__ sedge) {
    int b = blockIdx.x;
    int beg = bstart[b], end = bstart[b + 1];
    __shared__ int hist[256];
    __shared__ int scn[256];
    __shared__ int cursor[256];
    int t = threadIdx.x;
    hist[t] = 0;
    __syncthreads();
    for (int i = beg + t; i < end; i += 256)
        atomicAdd(&hist[((unsigned)tmp[i].x) >> 24], 1);
    __syncthreads();
    int h = hist[t];
    scn[t] = h;
    __syncthreads();
    for (int off = 1; off < 256; off <<= 1) {
        int x = (t >= off) ? scn[t - off] : 0;
        __syncthreads();
        scn[t] += x;
        __syncthreads();
    }
    int excl = scn[t] - h;
    cursor[t] = excl;
    int row_id = b * 256 + t;
    if (row_id <= N_TOT) row_ptr[row_id] = beg + excl;
    __syncthreads();
    for (int i = beg + t; i < end; i += 256) {
        int2 rec = tmp[i];
        int lr = ((unsigned)rec.x) >> 24;
        int col = rec.x & 0xFFFFFF;
        int p = beg + atomicAdd(&cursor[lr], 1);
        sedge[p] = make_int2(col, rec.y);
    }
}

// ---------------- SpMM: 2 rows per wave, half2 per lane ----------------
// lanes 0-31 own row 2*wid2, lanes 32-63 own row 2*wid2+1.
// Each lane covers feature pair (2*sub, 2*sub+1): one dword gather + 2 FMAs.

__global__ __launch_bounds__(256) void spmm2_kernel(const int* __restrict__ row_ptr,
                                                    const int2* __restrict__ sedge,
                                                    const __half2* __restrict__ src,
                                                    __half2* __restrict__ dst,
                                                    const __half2* __restrict__ b0,
                                                    const __half2* __restrict__ b1,
                                                    float* __restrict__ acc,
                                                    int last) {
    int wid2 = (blockIdx.x * blockDim.x + threadIdx.x) >> 6;
    int lane = threadIdx.x & 63;
    int h = lane >> 5;
    int sub = lane & 31;
    int row = wid2 * 2 + h;
    if (row >= N_TOT) return;
    int beg = row_ptr[row];
    int end = row_ptr[row + 1];
    float s0 = 0.0f, s1 = 0.0f;
    for (int base = beg; base < end; base += 32) {
        int cnt = min(32, end - base);
        int2 e = make_int2(0, 0);
        if (sub < cnt) e = sedge[base + sub];
        for (int j0 = 0; j0 < cnt; j0 += 8) {
#pragma unroll
            for (int k = 0; k < 8; ++k) {
                int jj = j0 + k;
                int sl = (h << 5) | ((jj < cnt) ? jj : 0);
                int col = __shfl(e.x, sl);
                float vv = __int_as_float(__shfl(e.y, sl));
                if (jj >= cnt) vv = 0.0f;
                float2 f = __half22float2(src[(unsigned)(col * 32 + sub)]);
                s0 = fmaf(vv, f.x, s0);
                s1 = fmaf(vv, f.y, s1);
            }
        }
    }
    unsigned o = (unsigned)(row * 32 + sub);
    if (last) {
        float2 f0 = __half22float2(b0[o]);
        float2 f1 = __half22float2(b1[o]);
        float2 f2 = __half22float2(src[o]);
        float2 r;
        r.x = (f0.x + f1.x + f2.x + s0) * 0.25f;
        r.y = (f0.y + f1.y + f2.y + s1) * 0.25f;
        reinterpret_cast<float2*>(acc)[o] = r;
    } else {
        dst[o] = __floats2half2_rn(s0, s1);
    }
}

// ---------------- fallback (fp32 atomic path, used only if ws too small) ----------------

__global__ void initf_kernel(const float* __restrict__ user_emb,
                             const float* __restrict__ item_emb,
                             float* __restrict__ cur,
                             float* __restrict__ acc) {
    int i = blockIdx.x * blockDim.x + threadIdx.x;
    const int total = N_TOT * DIM;
    if (i < total) {
        float v = (i < N_USERS * DIM) ? user_emb[i] : item_emb[i - N_USERS * DIM];
        cur[i] = v;
        acc[i] = v;
    }
}

__global__ void zero_f_kernel(float* __restrict__ p, int n) {
    int i = blockIdx.x * blockDim.x + threadIdx.x;
    if (i < n) p[i] = 0.0f;
}

__global__ void spmm_atomic_kernel(const int* __restrict__ rows, const int* __restrict__ cols,
                                   const float* __restrict__ vals,
                                   const float* __restrict__ cur, float* __restrict__ next) {
    int tid = blockIdx.x * blockDim.x + threadIdx.x;
    int e = tid >> 4;
    int q = (tid & 15) << 2;
    if (e < E_EDGES) {
        int r = rows[e];
        int c = cols[e];
        float v = vals[e];
        const float4 x = *reinterpret_cast<const float4*>(cur + (size_t)c * DIM + q);
        float* dst = next + (size_t)r * DIM + q;
        atomicAdd(dst + 0, v * x.x);
        atomicAdd(dst + 1, v * x.y);
        atomicAdd(dst + 2, v * x.z);
        atomicAdd(dst + 3, v * x.w);
    }
}

__global__ void accum_kernel(float* __restrict__ acc, const float* __restrict__ next, int n) {
    int i = blockIdx.x * blockDim.x + threadIdx.x;
    if (i < n) acc[i] += next[i];
}

__global__ void scale_kernel(float* __restrict__ acc, int n) {
    int i = blockIdx.x * blockDim.x + threadIdx.x;
    if (i < n) acc[i] *= 0.25f;
}

// ---------------- launch ----------------

extern "C" void kernel_launch(void* const* d_in, const int* in_sizes, int n_in,
                              void* d_out, int out_size, void* d_ws, size_t ws_size,
                              hipStream_t stream) {
    const int*   rows     = (const int*)d_in[0];
    const int*   cols     = (const int*)d_in[1];
    const float* vals     = (const float*)d_in[2];
    const float* user_emb = (const float*)d_in[3];
    const float* item_emb = (const float*)d_in[4];
    float* acc = (float*)d_out;

    const int total  = N_TOT * DIM;
    const int total2 = total / 2;          // half2 count per buffer
    const int tb = 256;

    // workspace layout; tmp (24 MB) overlays b0+b1 (38.4 MB) — tmp dead
    // before init_kernel writes b0 (init runs after sort_kernel).
    __half2* b0 = (__half2*)d_ws;
    __half2* b1 = b0 + (size_t)total2;
    __half2* b2 = b1 + (size_t)total2;
    int2*  tmp = (int2*)d_ws;
    int2*  sedge   = (int2*)(b2 + (size_t)total2);
    int*   row_ptr = (int*)(sedge + (size_t)E_EDGES);
    int*   hist1   = row_ptr + NP1;
    int*   fill1   = hist1 + NB1;
    int*   bstart  = fill1 + NB1;                   // NB1+1 ints
    size_t need = (size_t)((char*)(bstart + NB1 + 1) - (char*)d_ws);

    const int grid_bin = (E_EDGES + EPB - 1) / EPB;  // 733

    if (ws_size >= need) {
        zero_int_kernel<<<(2 * NB1 + tb - 1) / tb, tb, 0, stream>>>(hist1, 2 * NB1);
        hist1_kernel<<<grid_bin, tb, 0, stream>>>(rows, hist1);
        bscan_kernel<<<1, tb, 0, stream>>>(hist1, bstart);
        bin_kernel<<<grid_bin, tb, 0, stream>>>(rows, cols, vals, bstart, fill1, tmp);
        sort_kernel<<<NB1, tb, 0, stream>>>(tmp, bstart, row_ptr, sedge);

        dim3 blkInit((total / 4 + tb - 1) / tb);
        init_kernel<<<blkInit, tb, 0, stream>>>(user_emb, item_emb, b0);

        // one wave per 2 rows
        const int waves = N_TOT / 2;                 // 75000
        dim3 blkRows((waves * 64 + tb - 1) / tb);    // 18750
        spmm2_kernel<<<blkRows, tb, 0, stream>>>(row_ptr, sedge, b0, b1, b0, b0, acc, 0);
        spmm2_kernel<<<blkRows, tb, 0, stream>>>(row_ptr, sedge, b1, b2, b0, b0, acc, 0);
        spmm2_kernel<<<blkRows, tb, 0, stream>>>(row_ptr, sedge, b2, b2, b0, b1, acc, 1);
    } else {
        // fallback: fp32 atomic scatter path
        float* fcur = (float*)d_ws;
        float* fnxt = fcur + (size_t)total;
        dim3 blkTotal((total + tb - 1) / tb);
        initf_kernel<<<blkTotal, tb, 0, stream>>>(user_emb, item_emb, fcur, acc);
        const long long spmm_threads = (long long)E_EDGES * 16;
        dim3 blkSpmm((unsigned)((spmm_threads + tb - 1) / tb));
        for (int layer = 0; layer < 3; ++layer) {
            zero_f_kernel<<<blkTotal, tb, 0, stream>>>(fnxt, total);
            spmm_atomic_kernel<<<blkSpmm, tb, 0, stream>>>(rows, cols, vals, fcur, fnxt);
            accum_kernel<<<blkTotal, tb, 0, stream>>>(acc, fnxt, total);
            float* t = fcur; fcur = fnxt; fnxt = t;
        }
        scale_kernel<<<blkTotal, tb, 0, stream>>>(acc, total);
    }
}